// Round 11
// baseline (662.539 us; speedup 1.0000x reference)
//
#include <hip/hip_runtime.h>
#include <cstdint>
#include <cstddef>

// ---- problem constants (fixed by setup_inputs) ----
#define B_   8
#define N_   8192
#define S_   2048
#define C1_  128
#define C2_  256
#define CIN_ 384      // C1 + C2
#define M_   65536    // B_ * N_
#define NOUT_ 512
#define SCH_ 8                 // S-chunks for knn parallelism
#define CPTS (S_ / SCH_)       // 256 points per chunk

typedef unsigned short u16;
typedef __attribute__((ext_vector_type(8))) short short8;
typedef __attribute__((ext_vector_type(4))) short short4v;
typedef __attribute__((ext_vector_type(4))) float f32x4;

__device__ __forceinline__ u16 f2bf(float f) {       // RNE
  uint32_t u = __float_as_uint(f);
  u += 0x7fffu + ((u >> 16) & 1u);
  return (u16)(u >> 16);
}
__device__ __forceinline__ float bf2f(u16 h) {
  return __uint_as_float(((uint32_t)h) << 16);
}
// hi = truncated top-16, lo = RNE remainder; ~2^-17 relative total error.
__device__ __forceinline__ void split2(float v, u16& h, u16& l) {
  uint32_t u = __float_as_uint(v);
  h = (u16)(u >> 16);
  float hf = __uint_as_float(u & 0xffff0000u);
  l = f2bf(v - hf);
}
// packed u32: low16 = hi-bf16, high16 = lo-bf16
__device__ __forceinline__ uint32_t packsplit(float v) {
  u16 h, l; split2(v, h, l);
  return ((uint32_t)l << 16) | (uint32_t)h;
}
__device__ __forceinline__ float unpacksplit(uint32_t w) {
  return bf2f((u16)(w & 0xffffu)) + bf2f((u16)(w >> 16));
}
__device__ __forceinline__ void gload16(const void* g, void* l) {
  __builtin_amdgcn_global_load_lds(
      (const __attribute__((address_space(1))) uint32_t*)g,
      (__attribute__((address_space(3))) uint32_t*)l, 16, 0, 0);
}

// =====================================================================
// Kernel 1a: per-chunk branchless top-3.  grid (M/256, SCH_), 256 thr.
// =====================================================================
__global__ __launch_bounds__(256) void knn_kernel(
    const float* __restrict__ xyz1, const float* __restrict__ xyz2,
    float* __restrict__ candD, int* __restrict__ candI)
{
  __shared__ float4 s4[CPTS];      // 4 KB
  const int t  = threadIdx.x;
  const int q  = blockIdx.x * 256 + t;
  const int b  = q >> 13;                  // N_ = 8192
  const int ch = blockIdx.y;
  const int jb = ch * CPTS;

  {
    const float* p = xyz2 + ((size_t)b * S_ + jb + t) * 3;
    float px = p[0], py = p[1], pz = p[2];
    float nn = __fadd_rn(__fadd_rn(__fmul_rn(px, px), __fmul_rn(py, py)), __fmul_rn(pz, pz));
    s4[t] = make_float4(px, py, pz, nn);
  }
  __syncthreads();

  const float* p1 = xyz1 + (size_t)q * 3;
  const float ax = p1[0], ay = p1[1], az = p1[2];
  const float na = __fadd_rn(__fadd_rn(__fmul_rn(ax, ax), __fmul_rn(ay, ay)), __fmul_rn(az, az));

  float d0 = 3.0e38f, d1 = 3.0e38f, d2 = 3.0e38f;
  int   i0 = 0, i1 = 0, i2 = 0;
  #pragma unroll 4
  for (int j = 0; j < CPTS; ++j) {
    float4 p = s4[j];
    float ab = __fmaf_rn(az, p.z, __fmaf_rn(ay, p.y, __fmul_rn(ax, p.x)));
    float d  = __fadd_rn(__fadd_rn(na, p.w), __fmul_rn(-2.0f, ab));
    bool lt0 = d < d0, lt1 = d < d1, lt2 = d < d2;
    int  jg  = jb + j;
    d2 = lt1 ? d1 : (lt2 ? d : d2);  i2 = lt1 ? i1 : (lt2 ? jg : i2);
    d1 = lt0 ? d0 : (lt1 ? d : d1);  i1 = lt0 ? i0 : (lt1 ? jg : i1);
    d0 = lt0 ? d  : d0;              i0 = lt0 ? jg : i0;
  }
  candD[(size_t)(ch * 3 + 0) * M_ + q] = d0;
  candD[(size_t)(ch * 3 + 1) * M_ + q] = d1;
  candD[(size_t)(ch * 3 + 2) * M_ + q] = d2;
  candI[(size_t)(ch * 3 + 0) * M_ + q] = i0;
  candI[(size_t)(ch * 3 + 1) * M_ + q] = i1;
  candI[(size_t)(ch * 3 + 2) * M_ + q] = i2;
}

// =====================================================================
// Kernel 1b: merge 8x3 candidates (chunk-major, strict <) -> weights.
// =====================================================================
__global__ __launch_bounds__(256) void merge_kernel(
    const float* __restrict__ candD, const int* __restrict__ candI,
    float* __restrict__ wiW, int* __restrict__ wiI)
{
  const int q = blockIdx.x * 256 + threadIdx.x;
  float d0 = 3.0e38f, d1 = 3.0e38f, d2 = 3.0e38f;
  int   i0 = 0, i1 = 0, i2 = 0;
  #pragma unroll
  for (int s = 0; s < 3 * SCH_; ++s) {
    float d = candD[(size_t)s * M_ + q];
    int   i = candI[(size_t)s * M_ + q];
    bool lt0 = d < d0, lt1 = d < d1, lt2 = d < d2;
    d2 = lt1 ? d1 : (lt2 ? d : d2);  i2 = lt1 ? i1 : (lt2 ? i : i2);
    d1 = lt0 ? d0 : (lt1 ? d : d1);  i1 = lt0 ? i0 : (lt1 ? i : i1);
    d0 = lt0 ? d  : d0;              i0 = lt0 ? i : i0;
  }
  d0 = fmaxf(d0, 0.0f); d1 = fmaxf(d1, 0.0f); d2 = fmaxf(d2, 0.0f);
  float w0 = 1.0f / (d0 + 1e-8f);
  float w1 = 1.0f / (d1 + 1e-8f);
  float w2 = 1.0f / (d2 + 1e-8f);
  float ws = __fadd_rn(__fadd_rn(w0, w1), w2);
  wiW[q] = w0 / ws; wiW[M_ + q] = w1 / ws; wiW[2 * M_ + q] = w2 / ws;
  wiI[q] = i0;      wiI[M_ + q] = i1;      wiI[2 * M_ + q] = i2;
}

// =====================================================================
// Kernel 1c: gather + interpolate + concat -> xhl rows [hi384|lo384].
// =====================================================================
__global__ __launch_bounds__(256) void gather_kernel(
    const float* __restrict__ points1, const float* __restrict__ points2,
    const float* __restrict__ wiW, const int* __restrict__ wiI,
    u16* __restrict__ xhl)
{
  const int t = threadIdx.x;
  const int q = blockIdx.x * 4 + (t >> 6);
  const int c = t & 63;
  const int b = q >> 13;
  const int j0 = wiI[q], j1 = wiI[M_ + q], j2 = wiI[2 * M_ + q];
  const float v0 = wiW[q], v1 = wiW[M_ + q], v2 = wiW[2 * M_ + q];
  const float* p2b = points2 + (size_t)b * S_ * C2_;
  float4 r0 = *(const float4*)(p2b + (size_t)j0 * C2_ + 4 * c);
  float4 r1 = *(const float4*)(p2b + (size_t)j1 * C2_ + 4 * c);
  float4 r2 = *(const float4*)(p2b + (size_t)j2 * C2_ + 4 * c);
  u16* row = xhl + (size_t)q * 768;
  short4v hv, lv;
  {
    float f;
    u16 h, l;
    f = __fadd_rn(__fadd_rn(__fmul_rn(r0.x, v0), __fmul_rn(r1.x, v1)), __fmul_rn(r2.x, v2));
    split2(f, h, l); hv[0] = (short)h; lv[0] = (short)l;
    f = __fadd_rn(__fadd_rn(__fmul_rn(r0.y, v0), __fmul_rn(r1.y, v1)), __fmul_rn(r2.y, v2));
    split2(f, h, l); hv[1] = (short)h; lv[1] = (short)l;
    f = __fadd_rn(__fadd_rn(__fmul_rn(r0.z, v0), __fmul_rn(r1.z, v1)), __fmul_rn(r2.z, v2));
    split2(f, h, l); hv[2] = (short)h; lv[2] = (short)l;
    f = __fadd_rn(__fadd_rn(__fmul_rn(r0.w, v0), __fmul_rn(r1.w, v1)), __fmul_rn(r2.w, v2));
    split2(f, h, l); hv[3] = (short)h; lv[3] = (short)l;
  }
  *(short4v*)(row + 128 + 4 * c) = hv;
  *(short4v*)(row + 512 + 4 * c) = lv;
  if (c < 32) {
    float4 p = *(const float4*)(points1 + (size_t)q * C1_ + 4 * c);
    short4v ph, pl;
    u16 h, l;
    split2(p.x, h, l); ph[0] = (short)h; pl[0] = (short)l;
    split2(p.y, h, l); ph[1] = (short)h; pl[1] = (short)l;
    split2(p.z, h, l); ph[2] = (short)h; pl[2] = (short)l;
    split2(p.w, h, l); ph[3] = (short)h; pl[3] = (short)l;
    *(short4v*)(row + 4 * c) = ph;
    *(short4v*)(row + 384 + 4 * c) = pl;
  }
}

// =====================================================================
// Kernel 2: W1 fp32 -> [hi K | lo K] bf16 rows
// =====================================================================
__global__ __launch_bounds__(128) void wconv_kernel(
    const float* __restrict__ W, u16* __restrict__ Whl, int K)
{
  int c = blockIdx.x * 128 + threadIdx.x;
  int o = blockIdx.y;
  float w = W[(size_t)o * K + c];
  u16 h, l; split2(w, h, l);
  Whl[(size_t)o * 2 * K + c] = h;
  Whl[(size_t)o * 2 * K + K + c] = l;
}

// =====================================================================
// Kernel 3: bf16-split MFMA GEMM (m97 2-barrier shape).
//   MODE 0 (gemm1): A = split-u16 rows [hi K|lo K] (gload_lds direct);
//                   B = split-u16 rows (gload_lds direct).
//   MODE 1 (gemm2): A = PACKED u32 y1 + fused BN1+ReLU in staging;
//                   B = fp32 W2 converted in staging.
//   Output: packed u32 (lo<<16|hi) + fused BN-stat accumulation.
//   Grid (M/128, 4): consecutive blocks share the B panel (L2 affinity).
// =====================================================================
template<int K, int MODE>
__global__ __launch_bounds__(256) void gemm_kernel(
    const u16* __restrict__ Au, const uint32_t* __restrict__ Ap,
    const u16* __restrict__ Bu, const float* __restrict__ Bf,
    const float* __restrict__ bias,
    const float* __restrict__ aSc, const float* __restrict__ aSh,
    uint32_t* __restrict__ Yp, float* __restrict__ sumOut, float* __restrict__ sqOut)
{
  __shared__ __align__(16) u16 sAh[4096], sAl[4096], sBh[4096], sBl[4096]; // 8 KB each
  __shared__ float sred[256];
  __shared__ float sSc[MODE ? K : 1];
  __shared__ float sSh[MODE ? K : 1];
  static_assert(K % 32 == 0, "");

  const int t  = threadIdx.x;
  const int m0 = blockIdx.x * 128;
  const int n0 = blockIdx.y * 128;
  const int l  = t & 63, lr = l & 15, lq = l >> 4;
  const int wid = t >> 6, wm = wid >> 1, wn = wid & 1;

  if constexpr (MODE) {
    for (int i = t; i < K; i += 256) { sSc[i] = aSc[i]; sSh[i] = aSh[i]; }
    __syncthreads();
  }

  f32x4 acc[4][4];
  #pragma unroll
  for (int i = 0; i < 4; ++i)
    #pragma unroll
    for (int j = 0; j < 4; ++j) acc[i][j] = (f32x4){0.f, 0.f, 0.f, 0.f};

  for (int kt = 0; kt < K; kt += 32) {
    if constexpr (MODE == 0) {
      #pragma unroll
      for (int i = 0; i < 2; ++i) {
        int u = i * 256 + t;
        int row = u >> 2, sl = u & 3;
        const u16* srcA = Au + (size_t)(m0 + row) * (2 * K) + kt + sl * 8;
        gload16(srcA,     (char*)sAh + u * 16);
        gload16(srcA + K, (char*)sAl + u * 16);
        const u16* srcB = Bu + (size_t)(n0 + row) * (2 * K) + kt + sl * 8;
        gload16(srcB,     (char*)sBh + u * 16);
        gload16(srcB + K, (char*)sBl + u * 16);
      }
    } else {
      // A: packed u32 + BN1 + ReLU + re-split
      #pragma unroll
      for (int i = 0; i < 2; ++i) {
        int u = i * 256 + t;
        int row = u >> 2, sl = u & 3;
        const uint32_t* src = Ap + (size_t)(m0 + row) * K + kt + sl * 8;
        uint4 v0 = *(const uint4*)src;
        uint4 v1 = *(const uint4*)(src + 4);
        uint32_t w8[8] = {v0.x, v0.y, v0.z, v0.w, v1.x, v1.y, v1.z, v1.w};
        short8 hv, lv;
        #pragma unroll
        for (int j = 0; j < 8; ++j) {
          int col = kt + sl * 8 + j;
          float f = unpacksplit(w8[j]);
          float z = fmaxf(__fmaf_rn(f, sSc[col], sSh[col]), 0.0f);
          u16 h, lo; split2(z, h, lo);
          hv[j] = (short)h; lv[j] = (short)lo;
        }
        *(short8*)((char*)sAh + u * 16) = hv;
        *(short8*)((char*)sAl + u * 16) = lv;
      }
      // B: fp32 W2 -> split
      #pragma unroll
      for (int i = 0; i < 4; ++i) {
        int u = i * 256 + t;
        int row = u >> 3, c4 = (u & 7) * 4;
        float4 w4 = *(const float4*)(Bf + (size_t)(n0 + row) * K + kt + c4);
        short4v h4, l4;
        u16 h, lo;
        split2(w4.x, h, lo); h4[0] = (short)h; l4[0] = (short)lo;
        split2(w4.y, h, lo); h4[1] = (short)h; l4[1] = (short)lo;
        split2(w4.z, h, lo); h4[2] = (short)h; l4[2] = (short)lo;
        split2(w4.w, h, lo); h4[3] = (short)h; l4[3] = (short)lo;
        *(short4v*)((char*)sBh + row * 64 + c4 * 2) = h4;
        *(short4v*)((char*)sBl + row * 64 + c4 * 2) = l4;
      }
    }
    __syncthreads();

    const int abase = (wm * 64 + lr) * 64 + lq * 16;   // byte offsets
    const int bbase = (wn * 64 + lr) * 64 + lq * 16;
    short8 bh[4], bl[4];
    #pragma unroll
    for (int ni = 0; ni < 4; ++ni) {
      bh[ni] = *(const short8*)((const char*)sBh + bbase + ni * 1024);
      bl[ni] = *(const short8*)((const char*)sBl + bbase + ni * 1024);
    }
    #pragma unroll
    for (int mi = 0; mi < 4; ++mi) {
      short8 ah = *(const short8*)((const char*)sAh + abase + mi * 1024);
      short8 al = *(const short8*)((const char*)sAl + abase + mi * 1024);
      #pragma unroll
      for (int ni = 0; ni < 4; ++ni) {
        acc[mi][ni] = __builtin_amdgcn_mfma_f32_16x16x32_bf16(ah, bh[ni], acc[mi][ni], 0, 0, 0);
        acc[mi][ni] = __builtin_amdgcn_mfma_f32_16x16x32_bf16(ah, bl[ni], acc[mi][ni], 0, 0, 0);
        acc[mi][ni] = __builtin_amdgcn_mfma_f32_16x16x32_bf16(al, bh[ni], acc[mi][ni], 0, 0, 0);
      }
    }
    __syncthreads();
  }

  // ---- epilogue: bias, packed u32 store, BN stats ----
  sred[t] = 0.f;
  __syncthreads();

  float bj[4];
  #pragma unroll
  for (int ni = 0; ni < 4; ++ni) bj[ni] = bias[n0 + wn * 64 + ni * 16 + lr];

  float colS[4] = {0.f, 0.f, 0.f, 0.f}, colQ[4] = {0.f, 0.f, 0.f, 0.f};
  #pragma unroll
  for (int mi = 0; mi < 4; ++mi) {
    #pragma unroll
    for (int q = 0; q < 4; ++q) {
      int m = m0 + wm * 64 + mi * 16 + lq * 4 + q;
      uint32_t* yr = Yp + (size_t)m * NOUT_ + n0;
      #pragma unroll
      for (int ni = 0; ni < 4; ++ni) {
        int col = wn * 64 + ni * 16 + lr;
        float v = acc[mi][ni][q] + bj[ni];
        yr[col] = packsplit(v);
        colS[ni] += v;
        colQ[ni] = __fmaf_rn(v, v, colQ[ni]);
      }
    }
  }
  #pragma unroll
  for (int ni = 0; ni < 4; ++ni) {
    int col = wn * 64 + ni * 16 + lr;
    atomicAdd(&sred[col], colS[ni]);
    atomicAdd(&sred[128 + col], colQ[ni]);
  }
  __syncthreads();
  if (t < 128) {
    atomicAdd(&sumOut[n0 + t], sred[t]);
    atomicAdd(&sqOut[n0 + t], sred[128 + t]);
  }
}

// =====================================================================
// Kernel 4: BN stats -> scale/shift
// =====================================================================
__global__ void finalize_kernel(const float* __restrict__ sum, const float* __restrict__ sq,
                                const float* __restrict__ g, const float* __restrict__ be,
                                float* __restrict__ scale, float* __restrict__ shift)
{
  int c = blockIdx.x * 256 + threadIdx.x;
  if (c >= 512) return;
  const float invM = 1.0f / 65536.0f;
  float mean = sum[c] * invM;
  float var  = fmaxf(sq[c] * invM - mean * mean, 0.0f);
  float rstd = rsqrtf(var + 1e-5f);
  float sc   = g[c] * rstd;
  scale[c] = sc;
  shift[c] = __fmaf_rn(-mean, sc, be[c]);
}

// =====================================================================
// Kernel 5: final BN+ReLU, in-place (packed u32 row -> fp32 row).
// =====================================================================
__global__ __launch_bounds__(256) void bnrelu_kernel(
    uint32_t* __restrict__ y, const float* __restrict__ sc, const float* __restrict__ sh)
{
  const size_t row = blockIdx.x;
  uint32_t* ru = y + row * NOUT_;
  const int t = threadIdx.x;
  uint2 w = *(const uint2*)(ru + 2 * t);
  float2 scv = *(const float2*)(sc + 2 * t);
  float2 shv = *(const float2*)(sh + 2 * t);
  float v0 = unpacksplit(w.x);
  float v1 = unpacksplit(w.y);
  float o0 = fmaxf(__fmaf_rn(v0, scv.x, shv.x), 0.0f);
  float o1 = fmaxf(__fmaf_rn(v1, scv.y, shv.y), 0.0f);
  __syncthreads();
  *(float2*)((float*)ru + 2 * t) = make_float2(o0, o1);
}

// =====================================================================
extern "C" void kernel_launch(void* const* d_in, const int* in_sizes, int n_in,
                              void* d_out, int out_size, void* d_ws, size_t ws_size,
                              hipStream_t stream)
{
  const float* xyz1    = (const float*)d_in[0];
  const float* xyz2    = (const float*)d_in[1];
  const float* points1 = (const float*)d_in[2];
  const float* points2 = (const float*)d_in[3];
  const float* W1  = (const float*)d_in[4];
  const float* b1  = (const float*)d_in[5];
  const float* g1  = (const float*)d_in[6];
  const float* be1 = (const float*)d_in[7];
  const float* W2  = (const float*)d_in[8];
  const float* b2  = (const float*)d_in[9];
  const float* g2  = (const float*)d_in[10];
  const float* be2 = (const float*)d_in[11];

  // ws: stats (16 KB) + y1 packed (M x 512 u32 = 134.22 MB) — proven footprint
  float* wsf = (float*)d_ws;
  float* sum1 = wsf + 0,    *sq1 = wsf + 512,  *sc1 = wsf + 1024, *sh1 = wsf + 1536;
  float* sum2 = wsf + 2048, *sq2 = wsf + 2560, *sc2 = wsf + 3072, *sh2 = wsf + 3584;
  uint32_t* y1p = (uint32_t*)((char*)d_ws + 16384);

  // d_out staging (134,217,728 B total):
  //   w1hl  [0,          786,432)
  //   xhl   [786,432,    101,449,728)
  //   candD [101,449,728, 107,741,184)   24 x M floats
  //   candI [107,741,184, 114,032,640)   24 x M ints
  //   wiW   [114,032,640, 114,819,072)    3 x M floats
  //   wiI   [114,819,072, 115,605,504)    3 x M ints
  char* ob = (char*)d_out;
  u16*   w1hl = (u16*)ob;
  u16*   xhl  = (u16*)(ob + 786432);
  float* candD = (float*)(ob + 101449728);
  int*   candI = (int*)(ob + 107741184);
  float* wiW   = (float*)(ob + 114032640);
  int*   wiI   = (int*)(ob + 114819072);

  hipMemsetAsync(d_ws, 0, 16384, stream);

  wconv_kernel<<<dim3(CIN_ / 128, 512), 128, 0, stream>>>(W1, w1hl, CIN_);

  knn_kernel<<<dim3(M_ / 256, SCH_), 256, 0, stream>>>(xyz1, xyz2, candD, candI);
  merge_kernel<<<M_ / 256, 256, 0, stream>>>(candD, candI, wiW, wiI);
  gather_kernel<<<M_ / 4, 256, 0, stream>>>(points1, points2, wiW, wiI, xhl);

  gemm_kernel<CIN_, 0><<<dim3(M_ / 128, 4), 256, 0, stream>>>(
      xhl, nullptr, w1hl, nullptr, b1, nullptr, nullptr, y1p, sum1, sq1);

  finalize_kernel<<<2, 256, 0, stream>>>(sum1, sq1, g1, be1, sc1, sh1);

  // gemm2: A = y1 packed + fused BN1+ReLU; B = fp32 W2; out -> d_out (packed)
  gemm_kernel<NOUT_, 1><<<dim3(M_ / 128, 4), 256, 0, stream>>>(
      nullptr, y1p, nullptr, W2, b2, sc1, sh1, (uint32_t*)d_out, sum2, sq2);

  finalize_kernel<<<2, 256, 0, stream>>>(sum2, sq2, g2, be2, sc2, sh2);

  bnrelu_kernel<<<M_, 256, 0, stream>>>((uint32_t*)d_out, sc2, sh2);
}